// Round 10
// baseline (59.075 us; speedup 1.0000x reference)
//
#include <hip/hip_runtime.h>
#include <hip/hip_bf16.h>

typedef __bf16 bf16x8 __attribute__((ext_vector_type(8)));
typedef float f32x4 __attribute__((ext_vector_type(4)));
typedef unsigned short ushort4v __attribute__((ext_vector_type(4)));
typedef unsigned short ushort8v __attribute__((ext_vector_type(8)));

#define B_  16
#define C_  256
#define HW_ 4096
#define E_  8

__device__ inline unsigned short f2bf(float f) {
    unsigned int b = __builtin_bit_cast(unsigned int, f);
    b += 0x7FFFu + ((b >> 16) & 1u);   // RNE (inputs finite)
    return (unsigned short)(b >> 16);
}

// ---------------- K1: pooled[b][c] = mean_{h,w} inputs[b,c,h,w] ----------------
__global__ __launch_bounds__(256) void k_pool(const float* __restrict__ in,
                                              float* __restrict__ pooled) {
    int bc = blockIdx.x;
    const float* p = in + (size_t)bc * HW_;
    int t = threadIdx.x;
    float s = 0.f;
#pragma unroll
    for (int i = 0; i < 4; i++) {
        float4 v = *reinterpret_cast<const float4*>(p + (size_t)(t + i * 256) * 4);
        s += v.x + v.y + v.z + v.w;
    }
#pragma unroll
    for (int off = 32; off; off >>= 1) s += __shfl_down(s, off, 64);
    __shared__ float part[4];
    if ((t & 63) == 0) part[t >> 6] = s;
    __syncthreads();
    if (t == 0) pooled[bc] = (part[0] + part[1] + part[2] + part[3]) * (1.0f / HW_);
}

// ------- K2: gates (redundant per block) + Weff slice + biasE (dblk 0) ---------
__global__ __launch_bounds__(256) void k_wg(const float* __restrict__ pooled,
                                            const float* __restrict__ Wr,
                                            const float* __restrict__ br,
                                            const float* __restrict__ Wexp,
                                            const float* __restrict__ bexp,
                                            unsigned short* __restrict__ Weff,
                                            float* __restrict__ biasE) {
    __shared__ float pooledS[C_];      // 1 KB
    __shared__ float wrs[C_ * E_];     // 8 KB
    __shared__ float lgp[64];
    __shared__ float gL[E_];
    const int t = threadIdx.x;
    const int b = blockIdx.y, dblk = blockIdx.x;

    pooledS[t] = pooled[b * C_ + t];
#pragma unroll
    for (int i = 0; i < 2; ++i)
        reinterpret_cast<float4*>(wrs)[t + i * 256] =
            reinterpret_cast<const float4*>(Wr)[t + i * 256];
    __syncthreads();
    if (t < 64) {
        const int e = t & 7, seg = t >> 3;
        float s = 0.f;
#pragma unroll
        for (int c = seg * 32; c < seg * 32 + 32; ++c)
            s += pooledS[c] * wrs[c * E_ + e];
        lgp[t] = s;
    }
    __syncthreads();
    if (t == 0) {
        float w[E_];
        float m = -1e30f;
#pragma unroll
        for (int e = 0; e < E_; ++e) {
            float s = br[e];
#pragma unroll
            for (int k = 0; k < 8; ++k) s += lgp[k * 8 + e];
            w[e] = s; m = fmaxf(m, s);
        }
        float sum = 0.f;
#pragma unroll
        for (int e = 0; e < E_; ++e) { w[e] = __expf(w[e] - m); sum += w[e]; }
        float inv = 1.f / sum;
#pragma unroll
        for (int e = 0; e < E_; ++e) w[e] *= inv;
        int i0 = 0;
#pragma unroll
        for (int e = 1; e < E_; ++e) if (w[e] > w[i0]) i0 = e;
        int i1 = -1;
#pragma unroll
        for (int e = 0; e < E_; ++e) {
            if (e == i0) continue;
            if (i1 < 0 || w[e] > w[i1]) i1 = e;
        }
#pragma unroll
        for (int e = 0; e < E_; ++e)
            gL[e] = (e == i0 || e == i1) ? w[e] : 0.f;
    }
    __syncthreads();
    if (dblk == 0) {
        float s = 0.f;
#pragma unroll
        for (int e = 0; e < E_; ++e) s += gL[e] * bexp[e * C_ + t];
        biasE[b * C_ + t] = s;
    }
    const int dloc = t >> 5, cq = t & 31;
    const int d = dblk * 8 + dloc;
#pragma unroll
    for (int half = 0; half < 2; half++) {
        const int c = (cq + half * 32) * 4;
        float4 a = {0.f, 0.f, 0.f, 0.f};
#pragma unroll
        for (int e = 0; e < E_; e++) {
            float ge = gL[e];
            if (ge != 0.f) {
                float4 wv = *reinterpret_cast<const float4*>(
                    Wexp + ((size_t)(e * C_ + d)) * C_ + c);
                a.x += ge * wv.x; a.y += ge * wv.y;
                a.z += ge * wv.z; a.w += ge * wv.w;
            }
        }
        ushort4v o = { f2bf(a.x), f2bf(a.y), f2bf(a.z), f2bf(a.w) };
        *reinterpret_cast<ushort4v*>(Weff + ((size_t)(b * C_ + d)) * C_ + c) = o;
    }
}

// ---------------- K3: fused  out[b] = x + Weff[b] @ x + biasE[b] ---------------
// 512 threads (8 waves), N-tile 64, full K=256 in LDS (Bs, chunk-XOR-swizzled).
// Staging v2: direct transposed read (lane = 4 c-consecutive scalars at one p),
// pack ushort4, ONE swizzled 8-B ds_write. One barrier total. LDS 33 KB.
__global__ __launch_bounds__(512, 8) void k_fused(const float* __restrict__ in,
                                                  const unsigned short* __restrict__ Weff,
                                                  const float* __restrict__ biasE,
                                                  float* __restrict__ out) {
    __shared__ unsigned short Bs[64 * 256];   // 32 KB [p][c] bf16, chunk-XOR-swizzled
    __shared__ float biasS[C_];               // 1 KB

    const int t  = threadIdx.x;
    const int b  = blockIdx.y;
    const int n0 = blockIdx.x * 64;
    const int lane = t & 63, w = t >> 6;
    const int kg = lane >> 4, lr = lane & 15;
    const float* Xb = in + ((size_t)b * C_) * HW_ + n0;
    const unsigned short* Ab = Weff + (size_t)b * C_ * C_;

    if (t < C_) biasS[t] = biasE[b * C_ + t];

    // ---- stage: 64 tiles of 16c x 16p, tile T = it*8 + w ----
#pragma unroll
    for (int it = 0; it < 8; ++it) {
        const int T  = it * 8 + w;                       // wave-uniform
        const int c0 = (T & 15) * 16 + ((lane >> 4) << 2);
        const int p  = (T >> 4) * 16 + (lane & 15);
        const float* s = Xb + (size_t)c0 * HW_ + p;
        float x0 = s[0];
        float x1 = s[HW_];
        float x2 = s[2 * HW_];
        float x3 = s[3 * HW_];
        ushort4v u = { f2bf(x0), f2bf(x1), f2bf(x2), f2bf(x3) };
        const int lc = c0 >> 3, half = (c0 >> 2) & 1;
        const int cs = lc ^ (p & 7);                     // bijective per p-row
        *reinterpret_cast<ushort4v*>(&Bs[p * 256 + cs * 8 + half * 4]) = u;
    }
    __syncthreads();

    // ---- acc init: identity (from Bs) + bias ----
    f32x4 acc[2][4];
#pragma unroll
    for (int mi = 0; mi < 2; ++mi) {
#pragma unroll
        for (int j = 0; j < 4; ++j) {
            const int row = w * 32 + mi * 16 + kg * 4 + j;
            const float bias = biasS[row];
#pragma unroll
            for (int ni = 0; ni < 4; ++ni) {
                const int p = ni * 16 + lr;
                unsigned short xv =
                    Bs[p * 256 + (((row >> 3) ^ (p & 7)) * 8) + (row & 7)];
                acc[mi][ni][j] =
                    __builtin_bit_cast(float, (unsigned int)xv << 16) + bias;
            }
        }
    }

    // ---- MFMA main loop: 8 k-frags; A streamed from L2-resident Weff ----
#pragma unroll
    for (int kf = 0; kf < 8; ++kf) {
        bf16x8 af[2];
#pragma unroll
        for (int mi = 0; mi < 2; ++mi) {
            const int row = w * 32 + mi * 16 + lr;
            af[mi] = __builtin_bit_cast(bf16x8,
                *reinterpret_cast<const ushort8v*>(
                    &Ab[(size_t)row * C_ + kf * 32 + kg * 8]));
        }
#pragma unroll
        for (int ni = 0; ni < 4; ++ni) {
            const int p = ni * 16 + lr;
            const int cc = (kf * 4 + kg) ^ (p & 7);
            bf16x8 bfv = __builtin_bit_cast(bf16x8,
                *reinterpret_cast<const ushort8v*>(&Bs[p * 256 + cc * 8]));
            acc[0][ni] = __builtin_amdgcn_mfma_f32_16x16x32_bf16(
                af[0], bfv, acc[0][ni], 0, 0, 0);
            acc[1][ni] = __builtin_amdgcn_mfma_f32_16x16x32_bf16(
                af[1], bfv, acc[1][ni], 0, 0, 0);
        }
    }

    // ---- store ----
    float* outB = out + ((size_t)b * C_) * HW_ + n0;
#pragma unroll
    for (int mi = 0; mi < 2; ++mi) {
#pragma unroll
        for (int j = 0; j < 4; ++j) {
            const int row = w * 32 + mi * 16 + kg * 4 + j;
            float* orow = outB + (size_t)row * HW_;
#pragma unroll
            for (int ni = 0; ni < 4; ++ni)
                orow[ni * 16 + lr] = acc[mi][ni][j];
        }
    }
}

extern "C" void kernel_launch(void* const* d_in, const int* in_sizes, int n_in,
                              void* d_out, int out_size, void* d_ws, size_t ws_size,
                              hipStream_t stream) {
    const float* in   = (const float*)d_in[0];
    const float* Wr   = (const float*)d_in[1];
    const float* br   = (const float*)d_in[2];
    const float* Wexp = (const float*)d_in[3];
    const float* bexp = (const float*)d_in[4];
    float* out = (float*)d_out;
    char* ws = (char*)d_ws;

    float* pooled         = (float*)(ws);                    // 16 KB
    float* biasE          = (float*)(ws + 0x11000);          // 16 KB
    unsigned short* Weff  = (unsigned short*)(ws + 0x20000); // 2 MB

    hipLaunchKernelGGL(k_pool,  dim3(B_ * C_), dim3(256), 0, stream, in, pooled);
    hipLaunchKernelGGL(k_wg,    dim3(32, B_),  dim3(256), 0, stream,
                       pooled, Wr, br, Wexp, bexp, Weff, biasE);
    hipLaunchKernelGGL(k_fused, dim3(HW_ / 64, B_), dim3(512), 0, stream,
                       in, Weff, biasE, out);
}

// Round 11
// 54.322 us; speedup vs baseline: 1.0875x; 1.0875x over previous
//
#include <hip/hip_runtime.h>
#include <hip/hip_bf16.h>

typedef __bf16 bf16x8 __attribute__((ext_vector_type(8)));
typedef float f32x4 __attribute__((ext_vector_type(4)));
typedef unsigned short ushort4v __attribute__((ext_vector_type(4)));
typedef unsigned short ushort8v __attribute__((ext_vector_type(8)));

#define B_  16
#define C_  256
#define HW_ 4096
#define E_  8

__device__ inline unsigned short f2bf(float f) {
    unsigned int b = __builtin_bit_cast(unsigned int, f);
    b += 0x7FFFu + ((b >> 16) & 1u);   // RNE (inputs finite)
    return (unsigned short)(b >> 16);
}

// ---------------- K1: pooled[b][c] = mean_{h,w} inputs[b,c,h,w] ----------------
__global__ __launch_bounds__(256) void k_pool(const float* __restrict__ in,
                                              float* __restrict__ pooled) {
    int bc = blockIdx.x;
    const float* p = in + (size_t)bc * HW_;
    int t = threadIdx.x;
    float s = 0.f;
#pragma unroll
    for (int i = 0; i < 4; i++) {
        float4 v = *reinterpret_cast<const float4*>(p + (size_t)(t + i * 256) * 4);
        s += v.x + v.y + v.z + v.w;
    }
#pragma unroll
    for (int off = 32; off; off >>= 1) s += __shfl_down(s, off, 64);
    __shared__ float part[4];
    if ((t & 63) == 0) part[t >> 6] = s;
    __syncthreads();
    if (t == 0) pooled[bc] = (part[0] + part[1] + part[2] + part[3]) * (1.0f / HW_);
}

// ------- K2: gates + Weff slice (with identity folded in) + biasE --------------
__global__ __launch_bounds__(256) void k_wg(const float* __restrict__ pooled,
                                            const float* __restrict__ Wr,
                                            const float* __restrict__ br,
                                            const float* __restrict__ Wexp,
                                            const float* __restrict__ bexp,
                                            unsigned short* __restrict__ Weff,
                                            float* __restrict__ biasE) {
    __shared__ float pooledS[C_];      // 1 KB
    __shared__ float wrs[C_ * E_];     // 8 KB
    __shared__ float lgp[64];
    __shared__ float gL[E_];
    const int t = threadIdx.x;
    const int b = blockIdx.y, dblk = blockIdx.x;

    pooledS[t] = pooled[b * C_ + t];
#pragma unroll
    for (int i = 0; i < 2; ++i)
        reinterpret_cast<float4*>(wrs)[t + i * 256] =
            reinterpret_cast<const float4*>(Wr)[t + i * 256];
    __syncthreads();
    if (t < 64) {
        const int e = t & 7, seg = t >> 3;
        float s = 0.f;
#pragma unroll
        for (int c = seg * 32; c < seg * 32 + 32; ++c)
            s += pooledS[c] * wrs[c * E_ + e];
        lgp[t] = s;
    }
    __syncthreads();
    if (t == 0) {
        float w[E_];
        float m = -1e30f;
#pragma unroll
        for (int e = 0; e < E_; ++e) {
            float s = br[e];
#pragma unroll
            for (int k = 0; k < 8; ++k) s += lgp[k * 8 + e];
            w[e] = s; m = fmaxf(m, s);
        }
        float sum = 0.f;
#pragma unroll
        for (int e = 0; e < E_; ++e) { w[e] = __expf(w[e] - m); sum += w[e]; }
        float inv = 1.f / sum;
#pragma unroll
        for (int e = 0; e < E_; ++e) w[e] *= inv;
        int i0 = 0;
#pragma unroll
        for (int e = 1; e < E_; ++e) if (w[e] > w[i0]) i0 = e;
        int i1 = -1;
#pragma unroll
        for (int e = 0; e < E_; ++e) {
            if (e == i0) continue;
            if (i1 < 0 || w[e] > w[i1]) i1 = e;
        }
#pragma unroll
        for (int e = 0; e < E_; ++e)
            gL[e] = (e == i0 || e == i1) ? w[e] : 0.f;
    }
    __syncthreads();
    if (dblk == 0) {
        float s = 0.f;
#pragma unroll
        for (int e = 0; e < E_; ++e) s += gL[e] * bexp[e * C_ + t];
        biasE[b * C_ + t] = s;
    }
    const int dloc = t >> 5, cq = t & 31;
    const int d = dblk * 8 + dloc;
#pragma unroll
    for (int half = 0; half < 2; half++) {
        const int c = (cq + half * 32) * 4;
        float4 a = {0.f, 0.f, 0.f, 0.f};
#pragma unroll
        for (int e = 0; e < E_; e++) {
            float ge = gL[e];
            if (ge != 0.f) {
                float4 wv = *reinterpret_cast<const float4*>(
                    Wexp + ((size_t)(e * C_ + d)) * C_ + c);
                a.x += ge * wv.x; a.y += ge * wv.y;
                a.z += ge * wv.z; a.w += ge * wv.w;
            }
        }
        // fold identity: W' = Weff + I  (identity term then rides the MFMA)
        const int diff = d - c;
        if (diff == 0) a.x += 1.f;
        else if (diff == 1) a.y += 1.f;
        else if (diff == 2) a.z += 1.f;
        else if (diff == 3) a.w += 1.f;
        ushort4v o = { f2bf(a.x), f2bf(a.y), f2bf(a.z), f2bf(a.w) };
        *reinterpret_cast<ushort4v*>(Weff + ((size_t)(b * C_ + d)) * C_ + c) = o;
    }
}

// ---------------- K3: fused  out[b] = W'[b] @ x + biasE[b] ---------------------
// 512 threads (8 waves), N-tile 64, full K=256 in LDS (Bs, chunk-XOR-swizzled).
// Operand-swapped MFMA: D = X^T-frag * Weff-frag -> lane holds 4 consecutive p
// at one d -> float4 stores. Identity is inside Weff; acc starts at bias[d].
__global__ __launch_bounds__(512, 8) void k_fused(const float* __restrict__ in,
                                                  const unsigned short* __restrict__ Weff,
                                                  const float* __restrict__ biasE,
                                                  float* __restrict__ out) {
    __shared__ unsigned short Bs[64 * 256];   // 32 KB [p][c] bf16, chunk-XOR-swizzled
    __shared__ unsigned int   TsU[32 * 33];   // 4.2 KB p-pair-packed staging
    __shared__ float biasS[C_];               // 1 KB

    const int t  = threadIdx.x;
    const int b  = blockIdx.y;
    const int n0 = blockIdx.x * 64;
    const int lane = t & 63, w = t >> 6;
    const int kg = lane >> 4, lr = lane & 15;
    const float* Xb = in + ((size_t)b * C_) * HW_ + n0;
    const unsigned short* Ab = Weff + (size_t)b * C_ * C_;

    if (t < C_) biasS[t] = biasE[b * C_ + t];

    // ---- stage B = x^T bf16 into Bs: 8 passes of 32 c x 64 p (round-6 proven) ----
    {
        const int cl = t >> 4;              // 0..31 source c row (within pass)
        const int pq = (t & 15) * 4;        // 4 p per thread
        const int pr = t & 63;              // transpose-out p
        const int c8 = t >> 6;              // 0..7 (4-c group, wave-uniform)
        for (int pass = 0; pass < 8; ++pass) {
            float4 v = *reinterpret_cast<const float4*>(
                Xb + (size_t)(pass * 32 + cl) * HW_ + pq);
            unsigned int* tr = &TsU[cl * 33 + (t & 15) * 2];
            tr[0] = (unsigned int)f2bf(v.x) | ((unsigned int)f2bf(v.y) << 16);
            tr[1] = (unsigned int)f2bf(v.z) | ((unsigned int)f2bf(v.w) << 16);
            __syncthreads();
            const int half = pr & 1;
            ushort4v u;
#pragma unroll
            for (int j = 0; j < 4; ++j) {
                unsigned int wv = TsU[(c8 * 4 + j) * 33 + (pr >> 1)];
                u[j] = (unsigned short)(half ? (wv >> 16) : (wv & 0xffff));
            }
            const int lc = pass * 4 + (c8 >> 1);         // logical 8-short chunk
            const int cs = lc ^ (pr & 7);                // bijective per p-row
            *reinterpret_cast<ushort4v*>(&Bs[pr * 256 + cs * 8 + (c8 & 1) * 4]) = u;
            __syncthreads();
        }
    }

    // ---- acc init: bias[d] splat (d = col = w*32 + fd*16 + lr) ----
    f32x4 acc[2][4];
#pragma unroll
    for (int fd = 0; fd < 2; ++fd) {
        const float bias = biasS[w * 32 + fd * 16 + lr];
#pragma unroll
        for (int pf = 0; pf < 4; ++pf)
            acc[fd][pf] = (f32x4){bias, bias, bias, bias};
    }

    // ---- MFMA main loop: 8 k-frags; W-frags from L2-resident Weff ----
#pragma unroll
    for (int kf = 0; kf < 8; ++kf) {
        bf16x8 wf[2];
#pragma unroll
        for (int fd = 0; fd < 2; ++fd) {
            const int row = w * 32 + fd * 16 + lr;
            wf[fd] = __builtin_bit_cast(bf16x8,
                *reinterpret_cast<const ushort8v*>(
                    &Ab[(size_t)row * C_ + kf * 32 + kg * 8]));
        }
#pragma unroll
        for (int pf = 0; pf < 4; ++pf) {
            const int p = pf * 16 + lr;
            const int cc = (kf * 4 + kg) ^ (p & 7);
            bf16x8 xf = __builtin_bit_cast(bf16x8,
                *reinterpret_cast<const ushort8v*>(&Bs[p * 256 + cc * 8]));
            acc[0][pf] = __builtin_amdgcn_mfma_f32_16x16x32_bf16(
                xf, wf[0], acc[0][pf], 0, 0, 0);
            acc[1][pf] = __builtin_amdgcn_mfma_f32_16x16x32_bf16(
                xf, wf[1], acc[1][pf], 0, 0, 0);
        }
    }

    // ---- store: lane holds 4 consecutive p at one d -> float4 ----
    float* outB = out + ((size_t)b * C_) * HW_ + n0;
#pragma unroll
    for (int fd = 0; fd < 2; ++fd) {
        const int row = w * 32 + fd * 16 + lr;
        float* orow = outB + (size_t)row * HW_;
#pragma unroll
        for (int pf = 0; pf < 4; ++pf) {
            *reinterpret_cast<f32x4*>(&orow[pf * 16 + kg * 4]) = acc[fd][pf];
        }
    }
}

extern "C" void kernel_launch(void* const* d_in, const int* in_sizes, int n_in,
                              void* d_out, int out_size, void* d_ws, size_t ws_size,
                              hipStream_t stream) {
    const float* in   = (const float*)d_in[0];
    const float* Wr   = (const float*)d_in[1];
    const float* br   = (const float*)d_in[2];
    const float* Wexp = (const float*)d_in[3];
    const float* bexp = (const float*)d_in[4];
    float* out = (float*)d_out;
    char* ws = (char*)d_ws;

    float* pooled         = (float*)(ws);                    // 16 KB
    float* biasE          = (float*)(ws + 0x11000);          // 16 KB
    unsigned short* Weff  = (unsigned short*)(ws + 0x20000); // 2 MB

    hipLaunchKernelGGL(k_pool,  dim3(B_ * C_), dim3(256), 0, stream, in, pooled);
    hipLaunchKernelGGL(k_wg,    dim3(32, B_),  dim3(256), 0, stream,
                       pooled, Wr, br, Wexp, bexp, Weff, biasE);
    hipLaunchKernelGGL(k_fused, dim3(HW_ / 64, B_), dim3(512), 0, stream,
                       in, Weff, biasE, out);
}

// Round 12
// 53.229 us; speedup vs baseline: 1.1098x; 1.0205x over previous
//
#include <hip/hip_runtime.h>
#include <hip/hip_bf16.h>

typedef __bf16 bf16x8 __attribute__((ext_vector_type(8)));
typedef float f32x4 __attribute__((ext_vector_type(4)));
typedef unsigned short ushort4v __attribute__((ext_vector_type(4)));
typedef unsigned short ushort8v __attribute__((ext_vector_type(8)));

#define B_  16
#define C_  256
#define HW_ 4096
#define E_  8

__device__ inline unsigned short f2bf(float f) {
    unsigned int b = __builtin_bit_cast(unsigned int, f);
    b += 0x7FFFu + ((b >> 16) & 1u);   // RNE (inputs finite)
    return (unsigned short)(b >> 16);
}

// ---------------- K1: pooled[b][c] = mean_{h,w} inputs[b,c,h,w] ----------------
__global__ __launch_bounds__(256) void k_pool(const float* __restrict__ in,
                                              float* __restrict__ pooled) {
    int bc = blockIdx.x;
    const float* p = in + (size_t)bc * HW_;
    int t = threadIdx.x;
    float s = 0.f;
#pragma unroll
    for (int i = 0; i < 4; i++) {
        float4 v = *reinterpret_cast<const float4*>(p + (size_t)(t + i * 256) * 4);
        s += v.x + v.y + v.z + v.w;
    }
#pragma unroll
    for (int off = 32; off; off >>= 1) s += __shfl_down(s, off, 64);
    __shared__ float part[4];
    if ((t & 63) == 0) part[t >> 6] = s;
    __syncthreads();
    if (t == 0) pooled[bc] = (part[0] + part[1] + part[2] + part[3]) * (1.0f / HW_);
}

// ------- K2: gates + Weff slice (identity folded in) + biasE -------------------
__global__ __launch_bounds__(256) void k_wg(const float* __restrict__ pooled,
                                            const float* __restrict__ Wr,
                                            const float* __restrict__ br,
                                            const float* __restrict__ Wexp,
                                            const float* __restrict__ bexp,
                                            unsigned short* __restrict__ Weff,
                                            float* __restrict__ biasE) {
    __shared__ float pooledS[C_];      // 1 KB
    __shared__ float wrs[C_ * E_];     // 8 KB
    __shared__ float lgp[64];
    __shared__ float gL[E_];
    const int t = threadIdx.x;
    const int b = blockIdx.y, dblk = blockIdx.x;

    pooledS[t] = pooled[b * C_ + t];
#pragma unroll
    for (int i = 0; i < 2; ++i)
        reinterpret_cast<float4*>(wrs)[t + i * 256] =
            reinterpret_cast<const float4*>(Wr)[t + i * 256];
    __syncthreads();
    if (t < 64) {
        const int e = t & 7, seg = t >> 3;
        float s = 0.f;
#pragma unroll
        for (int c = seg * 32; c < seg * 32 + 32; ++c)
            s += pooledS[c] * wrs[c * E_ + e];
        lgp[t] = s;
    }
    __syncthreads();
    if (t == 0) {
        float w[E_];
        float m = -1e30f;
#pragma unroll
        for (int e = 0; e < E_; ++e) {
            float s = br[e];
#pragma unroll
            for (int k = 0; k < 8; ++k) s += lgp[k * 8 + e];
            w[e] = s; m = fmaxf(m, s);
        }
        float sum = 0.f;
#pragma unroll
        for (int e = 0; e < E_; ++e) { w[e] = __expf(w[e] - m); sum += w[e]; }
        float inv = 1.f / sum;
#pragma unroll
        for (int e = 0; e < E_; ++e) w[e] *= inv;
        int i0 = 0;
#pragma unroll
        for (int e = 1; e < E_; ++e) if (w[e] > w[i0]) i0 = e;
        int i1 = -1;
#pragma unroll
        for (int e = 0; e < E_; ++e) {
            if (e == i0) continue;
            if (i1 < 0 || w[e] > w[i1]) i1 = e;
        }
#pragma unroll
        for (int e = 0; e < E_; ++e)
            gL[e] = (e == i0 || e == i1) ? w[e] : 0.f;
    }
    __syncthreads();
    if (dblk == 0) {
        float s = 0.f;
#pragma unroll
        for (int e = 0; e < E_; ++e) s += gL[e] * bexp[e * C_ + t];
        biasE[b * C_ + t] = s;
    }
    const int dloc = t >> 5, cq = t & 31;
    const int d = dblk * 8 + dloc;
#pragma unroll
    for (int half = 0; half < 2; half++) {
        const int c = (cq + half * 32) * 4;
        float4 a = {0.f, 0.f, 0.f, 0.f};
#pragma unroll
        for (int e = 0; e < E_; e++) {
            float ge = gL[e];
            if (ge != 0.f) {
                float4 wv = *reinterpret_cast<const float4*>(
                    Wexp + ((size_t)(e * C_ + d)) * C_ + c);
                a.x += ge * wv.x; a.y += ge * wv.y;
                a.z += ge * wv.z; a.w += ge * wv.w;
            }
        }
        // fold identity: W' = Weff + I
        const int diff = d - c;
        if (diff == 0) a.x += 1.f;
        else if (diff == 1) a.y += 1.f;
        else if (diff == 2) a.z += 1.f;
        else if (diff == 3) a.w += 1.f;
        ushort4v o = { f2bf(a.x), f2bf(a.y), f2bf(a.z), f2bf(a.w) };
        *reinterpret_cast<ushort4v*>(Weff + ((size_t)(b * C_ + d)) * C_ + c) = o;
    }
}

// ---------------- K3: fused  out[b] = W'[b] @ x + biasE[b] ---------------------
// 512 threads (8 waves), N-tile 64, full K=256 in LDS (Bs, chunk-XOR-swizzled).
// Staging v3: barrier-free direct transpose — lane reads float2 from two adjacent
// c-rows, packs two (c,c+1)@p bf16 words, two direct swizzled ds_write_b32.
// One barrier total; loads pipeline freely. LDS 33 KB -> 4 blocks/CU.
__global__ __launch_bounds__(512, 8) void k_fused(const float* __restrict__ in,
                                                  const unsigned short* __restrict__ Weff,
                                                  const float* __restrict__ biasE,
                                                  float* __restrict__ out) {
    __shared__ unsigned short Bs[64 * 256];   // 32 KB [p][c] bf16, chunk-XOR-swizzled
    __shared__ float biasS[C_];               // 1 KB

    const int t  = threadIdx.x;
    const int b  = blockIdx.y;
    const int n0 = blockIdx.x * 64;
    const int lane = t & 63, w = t >> 6;
    const int kg = lane >> 4, lr = lane & 15;
    const float* Xb = in + ((size_t)b * C_) * HW_ + n0;
    const unsigned short* Ab = Weff + (size_t)b * C_ * C_;

    if (t < C_) biasS[t] = biasE[b * C_ + t];

    // ---- stage: 64 units of (8c x 32p); unit u = it*8 + w ----
    {
        const int dc = (lane >> 4) * 2;        // 0,2,4,6
        const int pl = (lane & 15) * 2;        // 0..30
#pragma unroll
        for (int it = 0; it < 8; ++it) {
            const int u = it * 8 + w;          // wave-uniform
            const int c_oct  = u & 31;         // logical chunk (c>>3)
            const int p_half = u >> 5;
            const int c = c_oct * 8 + dc;
            const int p = p_half * 32 + pl;
            const float* s = Xb + (size_t)c * HW_ + p;
            float2 v0 = *reinterpret_cast<const float2*>(s);        // (c, p/p+1)
            float2 v1 = *reinterpret_cast<const float2*>(s + HW_);  // (c+1, p/p+1)
            unsigned int ue = (unsigned int)f2bf(v0.x) | ((unsigned int)f2bf(v1.x) << 16);
            unsigned int uo = (unsigned int)f2bf(v0.y) | ((unsigned int)f2bf(v1.y) << 16);
            const int cse = c_oct ^ (p & 7);
            const int cso = c_oct ^ ((p + 1) & 7);
            *reinterpret_cast<unsigned int*>(&Bs[p * 256 + cse * 8 + dc]) = ue;
            *reinterpret_cast<unsigned int*>(&Bs[(p + 1) * 256 + cso * 8 + dc]) = uo;
        }
    }
    __syncthreads();

    // ---- acc init: bias[d] splat (d = col = w*32 + fd*16 + lr) ----
    f32x4 acc[2][4];
#pragma unroll
    for (int fd = 0; fd < 2; ++fd) {
        const float bias = biasS[w * 32 + fd * 16 + lr];
#pragma unroll
        for (int pf = 0; pf < 4; ++pf)
            acc[fd][pf] = (f32x4){bias, bias, bias, bias};
    }

    // ---- MFMA main loop: 8 k-frags; W-frags from L2-resident Weff ----
#pragma unroll
    for (int kf = 0; kf < 8; ++kf) {
        bf16x8 wf[2];
#pragma unroll
        for (int fd = 0; fd < 2; ++fd) {
            const int row = w * 32 + fd * 16 + lr;
            wf[fd] = __builtin_bit_cast(bf16x8,
                *reinterpret_cast<const ushort8v*>(
                    &Ab[(size_t)row * C_ + kf * 32 + kg * 8]));
        }
#pragma unroll
        for (int pf = 0; pf < 4; ++pf) {
            const int p = pf * 16 + lr;
            const int cc = (kf * 4 + kg) ^ (p & 7);
            bf16x8 xf = __builtin_bit_cast(bf16x8,
                *reinterpret_cast<const ushort8v*>(&Bs[p * 256 + cc * 8]));
            acc[0][pf] = __builtin_amdgcn_mfma_f32_16x16x32_bf16(
                xf, wf[0], acc[0][pf], 0, 0, 0);
            acc[1][pf] = __builtin_amdgcn_mfma_f32_16x16x32_bf16(
                xf, wf[1], acc[1][pf], 0, 0, 0);
        }
    }

    // ---- store: lane holds 4 consecutive p at one d -> float4 ----
    float* outB = out + ((size_t)b * C_) * HW_ + n0;
#pragma unroll
    for (int fd = 0; fd < 2; ++fd) {
        const int row = w * 32 + fd * 16 + lr;
        float* orow = outB + (size_t)row * HW_;
#pragma unroll
        for (int pf = 0; pf < 4; ++pf) {
            *reinterpret_cast<f32x4*>(&orow[pf * 16 + kg * 4]) = acc[fd][pf];
        }
    }
}

extern "C" void kernel_launch(void* const* d_in, const int* in_sizes, int n_in,
                              void* d_out, int out_size, void* d_ws, size_t ws_size,
                              hipStream_t stream) {
    const float* in   = (const float*)d_in[0];
    const float* Wr   = (const float*)d_in[1];
    const float* br   = (const float*)d_in[2];
    const float* Wexp = (const float*)d_in[3];
    const float* bexp = (const float*)d_in[4];
    float* out = (float*)d_out;
    char* ws = (char*)d_ws;

    float* pooled         = (float*)(ws);                    // 16 KB
    float* biasE          = (float*)(ws + 0x11000);          // 16 KB
    unsigned short* Weff  = (unsigned short*)(ws + 0x20000); // 2 MB

    hipLaunchKernelGGL(k_pool,  dim3(B_ * C_), dim3(256), 0, stream, in, pooled);
    hipLaunchKernelGGL(k_wg,    dim3(32, B_),  dim3(256), 0, stream,
                       pooled, Wr, br, Wexp, bexp, Weff, biasE);
    hipLaunchKernelGGL(k_fused, dim3(HW_ / 64, B_), dim3(512), 0, stream,
                       in, Weff, biasE, out);
}